// Round 3
// baseline (139.877 us; speedup 1.0000x reference)
//
#include <hip/hip_runtime.h>

#define NBLK 16
#define TPB  512
#define FLAGVAL 0x5A17C0DE
// ws float offsets
#define WS_NODE0 1024
#define WS_NODE1 2048
#define WS_NODE2 3072

__device__ __forceinline__ void gload16(const void* g, void* l) {
    __builtin_amdgcn_global_load_lds(
        (const __attribute__((address_space(1))) void*)g,
        (__attribute__((address_space(3))) void*)l, 16, 0, 0);
}

__device__ __forceinline__ void flag_set(int* wsI, int ph, int bid) {
    __threadfence();  // agent-scope: write back this XCD's L2
    __hip_atomic_store(&wsI[ph * 256 + bid * 16], FLAGVAL,
                       __ATOMIC_RELEASE, __HIP_MEMORY_SCOPE_AGENT);
}

__device__ __forceinline__ void flag_waitall(int* wsI, int ph, int t) {
    if (t < NBLK) {
        int c0 = 0;
        while (__hip_atomic_load(&wsI[ph * 256 + t * 16], __ATOMIC_ACQUIRE,
                                 __HIP_MEMORY_SCOPE_AGENT) != FLAGVAL &&
               ++c0 < (1 << 18)) {}   // failsafe: never hang the bench
    }
    __syncthreads();
}

// One ARMA layer, this block's 8-col slice. sA = [2][128][8] LDS weights.
__device__ __forceinline__ void arma_layer(
    int t, int bid, int cb, const float* sA, const float* __restrict__ ab,
    float* nodeL, const float* nrm, const int* earr, float* part, float* t12,
    float* wsF, int* wsI, int srcOff, int dstOff, int ph)
{
    nodeL[t] = wsF[srcOff + t];
    if (t < 384) nodeL[512 + t] = wsF[srcOff + 512 + t];
    __syncthreads();
    {
        int mat = t >> 8, rr = t & 255, c = rr & 7, k4 = rr >> 3;
        float acc[7] = {0.f, 0.f, 0.f, 0.f, 0.f, 0.f, 0.f};
        const float* Wm = &sA[mat * 1024];
        #pragma unroll
        for (int i = 0; i < 4; ++i) {
            int k = k4 * 4 + i;
            float wv = Wm[k * 8 + c];
            #pragma unroll
            for (int n = 0; n < 7; ++n) acc[n] = fmaf(nodeL[n * 128 + k], wv, acc[n]);
        }
        #pragma unroll
        for (int st = 8; st <= 32; st <<= 1) {
            #pragma unroll
            for (int n = 0; n < 7; ++n) acc[n] += __shfl_xor(acc[n], st);
        }
        int lane = t & 63;
        if ((lane >> 3) == 0) {            // k4-low==0 lanes hold the fold
            int wv4 = (t >> 6) & 3;
            float* P = &part[(mat * 4 + wv4) * 56 + c];
            #pragma unroll
            for (int n = 0; n < 7; ++n) P[n * 8] = acc[n];
        }
    }
    __syncthreads();
    if (t < 112) {
        int mat = t / 56, r = t % 56;
        t12[mat * 56 + r] = part[(mat * 4 + 0) * 56 + r] + part[(mat * 4 + 1) * 56 + r]
                          + part[(mat * 4 + 2) * 56 + r] + part[(mat * 4 + 3) * 56 + r];
    }
    __syncthreads();
    if (t < 56) {
        int n = t >> 3, c = t & 7;
        float agg = 0.f;
        #pragma unroll
        for (int e = 0; e < 14; ++e)
            if (earr[14 + e] == n) agg = fmaf(nrm[e], t12[earr[e] * 8 + c], agg);
        wsF[dstOff + n * 128 + cb + c] =
            fmaxf(agg + t12[56 + n * 8 + c] + ab[cb + c], 0.f);
    }
    __syncthreads();
    if (t == 0) flag_set(wsI, ph, bid);
}

__global__ __launch_bounds__(TPB) void gnn_mb(
    const float* __restrict__ x,
    const float* __restrict__ lW1, const float* __restrict__ lb1,
    const float* __restrict__ lW2, const float* __restrict__ lb2,
    const float* __restrict__ mW1, const float* __restrict__ mb1,
    const float* __restrict__ mW2, const float* __restrict__ mb2,
    const float* __restrict__ jW1, const float* __restrict__ jb1,
    const float* __restrict__ jW2, const float* __restrict__ jb2,
    const float* __restrict__ hW1, const float* __restrict__ hb1,
    const float* __restrict__ hW2, const float* __restrict__ hb2,
    const float* __restrict__ a1Wi, const float* __restrict__ a1Wr, const float* __restrict__ a1b,
    const float* __restrict__ a2Wi, const float* __restrict__ a2Wr, const float* __restrict__ a2b,
    const float* __restrict__ cW1, const float* __restrict__ cb1,
    const float* __restrict__ cW2, const float* __restrict__ cb2,
    const int* __restrict__ eidx,
    float* __restrict__ out, int* wsI, float* wsF)
{
    const int t = threadIdx.x;
    const int bid = blockIdx.x;
    const int w = t >> 6;
    const int lane = t & 63;
    const int cb = bid * 8;

    __shared__ float sW2[2048];   // [4 mats][64 k][8 c]
    __shared__ float sA1[2048];   // [2 mats][128 k][8 c]
    __shared__ float sA2[2048];
    __shared__ float nodeL[896], hidL[448], xin[28], nrm[14];
    __shared__ float part[512], t12[112], pooled[128], clsp[512];
    __shared__ int earr[28];

    // ---- t0: async prefetch this block's weight slices into LDS (3 chunks/wave).
    // chunk = 1 KB = 64 lanes x 16 B; global src per-lane strided (8-col slice),
    // LDS dest linear [k][8] (wave-uniform base + lane*16).
    for (int j = w; j < 24; j += 8) {
        const float* W; float* base; int h;
        if (j < 8)       { int m = j >> 1; h = j & 1;
                           W = (m == 0) ? lW2 : (m == 1) ? mW2 : (m == 2) ? jW2 : hW2;
                           base = &sW2[m * 512 + h * 256]; }
        else if (j < 16) { int m = (j - 8) >> 2; h = (j - 8) & 3;
                           W = m ? a1Wr : a1Wi;
                           base = &sA1[m * 1024 + h * 256]; }
        else             { int m = (j - 16) >> 2; h = (j - 16) & 3;
                           W = m ? a2Wr : a2Wi;
                           base = &sA2[m * 1024 + h * 256]; }
        const char* gp = (const char*)W +
            (size_t)((h * 32 + (lane >> 1)) * 512 + cb * 4 + (lane & 1) * 16);
        gload16(gp, base);
    }

    // ---- tiny demand loads
    if (t < 28) earr[t] = eidx[t];
    else if (t >= 64 && t < 92) xin[t - 64] = x[t - 64];   // row 0 of x only
    __syncthreads();

    // ---- MLP hidden layer (redundant per block, ~5 KB) + gcn_norm
    if (t < 448) {
        int n = t >> 6, j = t & 63;
        const float *W1, *b1; int din, off;
        if (n == 0)      { W1 = lW1; b1 = lb1; din = 3; off = 0;  }
        else if (n == 1) { W1 = mW1; b1 = mb1; din = 2; off = 3;  }
        else if (n <= 5) { W1 = jW1; b1 = jb1; din = 4; off = 5 + 4 * (n - 2); }
        else             { W1 = hW1; b1 = hb1; din = 7; off = 21; }
        float s = b1[j];
        for (int d = 0; d < din; ++d) s = fmaf(xin[off + d], W1[d * 64 + j], s);
        hidL[n * 64 + j] = fmaxf(s, 0.f);
    } else if (t < 462) {
        int e = t - 448;
        int sn = earr[e], dn = earr[14 + e], cs = 0, cd = 0;
        for (int k = 0; k < 14; ++k) { cs += (earr[14 + k] == sn); cd += (earr[14 + k] == dn); }
        nrm[e] = (1.0f / sqrtf((float)cs)) * (1.0f / sqrtf((float)cd));
    }
    asm volatile("s_waitcnt vmcnt(0)" ::: "memory");   // prefetch landed (per wave)
    __builtin_amdgcn_sched_barrier(0);
    __syncthreads();                                   // all waves' chunks visible

    // ---- node features: this block's 8 cols of stacked[0] (7x128)
    {
        int q = t >> 7, r = t & 127, c = r & 7, k2 = r >> 3;
        float a0 = 0.f, a1 = 0.f, a2 = 0.f, a3 = 0.f;
        const float* Wq = &sW2[q * 512];
        int nq = (q == 0) ? 0 : (q == 1) ? 1 : (q == 3) ? 6 : 2;
        #pragma unroll
        for (int i = 0; i < 4; ++i) {
            int k = k2 * 4 + i;
            float wv = Wq[k * 8 + c];
            if (q == 2) {                               // jets share jW2
                a0 = fmaf(hidL[2 * 64 + k], wv, a0);
                a1 = fmaf(hidL[3 * 64 + k], wv, a1);
                a2 = fmaf(hidL[4 * 64 + k], wv, a2);
                a3 = fmaf(hidL[5 * 64 + k], wv, a3);
            } else {
                a0 = fmaf(hidL[nq * 64 + k], wv, a0);
            }
        }
        #pragma unroll
        for (int st = 8; st <= 32; st <<= 1) {
            a0 += __shfl_xor(a0, st); a1 += __shfl_xor(a1, st);
            a2 += __shfl_xor(a2, st); a3 += __shfl_xor(a3, st);
        }
        if ((lane >> 3) == 0) {
            int wi = t >> 6;
            part[wi * 32 + 0 * 8 + c] = a0;
            part[wi * 32 + 1 * 8 + c] = a1;
            part[wi * 32 + 2 * 8 + c] = a2;
            part[wi * 32 + 3 * 8 + c] = a3;
        }
    }
    __syncthreads();
    if (t < 56) {
        int n = t >> 3, c = t & 7;
        int qn = (n == 0) ? 0 : (n == 1) ? 1 : (n == 6) ? 3 : 2;
        int an = (n >= 2 && n <= 5) ? (n - 2) : 0;
        float v = part[(2 * qn) * 32 + an * 8 + c] + part[(2 * qn + 1) * 32 + an * 8 + c];
        const float* b2 = (n == 0) ? lb2 : (n == 1) ? mb2 : (n == 6) ? hb2 : jb2;
        wsF[WS_NODE0 + n * 128 + cb + c] = v + b2[cb + c];
    }
    __syncthreads();
    if (t == 0) flag_set(wsI, 0, bid);
    flag_waitall(wsI, 0, t);

    // ---- ARMA layers
    arma_layer(t, bid, cb, sA1, a1b, nodeL, nrm, earr, part, t12,
               wsF, wsI, WS_NODE0, WS_NODE1, 1);
    flag_waitall(wsI, 1, t);
    arma_layer(t, bid, cb, sA2, a2b, nodeL, nrm, earr, part, t12,
               wsF, wsI, WS_NODE1, WS_NODE2, 2);
    if (bid != 0) return;
    flag_waitall(wsI, 2, t);

    // ---- block 0: pool + classifier
    nodeL[t] = wsF[WS_NODE2 + t];
    if (t < 384) nodeL[512 + t] = wsF[WS_NODE2 + 512 + t];
    __syncthreads();
    if (t < 128) {
        float m = nodeL[t];
        #pragma unroll
        for (int n = 1; n < 7; ++n) m = fmaxf(m, nodeL[n * 128 + t]);
        pooled[t] = m;
    }
    __syncthreads();
    {
        int j = t & 63, ks = t >> 6;
        float s = 0.f;
        #pragma unroll
        for (int i = 0; i < 16; ++i) {
            int k = ks * 16 + i;
            s = fmaf(pooled[k], cW1[k * 64 + j], s);
        }
        clsp[ks * 64 + j] = s;
    }
    __syncthreads();
    if (t < 64) {
        float s = cb1[t];
        #pragma unroll
        for (int q = 0; q < 8; ++q) s += clsp[q * 64 + t];
        float v = fmaxf(s, 0.f) * cW2[t];
        #pragma unroll
        for (int off = 32; off > 0; off >>= 1) v += __shfl_down(v, off);
        if (t == 0) out[0] = v + cb2[0];
    }
}

extern "C" void kernel_launch(void* const* d_in, const int* in_sizes, int n_in,
                              void* d_out, int out_size, void* d_ws, size_t ws_size,
                              hipStream_t stream) {
    (void)in_sizes; (void)n_in; (void)out_size; (void)ws_size;
    const float* x    = (const float*)d_in[0];
    const float* lW1  = (const float*)d_in[1];
    const float* lb1  = (const float*)d_in[2];
    const float* lW2  = (const float*)d_in[3];
    const float* lb2  = (const float*)d_in[4];
    const float* mW1  = (const float*)d_in[5];
    const float* mb1  = (const float*)d_in[6];
    const float* mW2  = (const float*)d_in[7];
    const float* mb2  = (const float*)d_in[8];
    const float* jW1  = (const float*)d_in[9];
    const float* jb1  = (const float*)d_in[10];
    const float* jW2  = (const float*)d_in[11];
    const float* jb2  = (const float*)d_in[12];
    const float* hW1  = (const float*)d_in[13];
    const float* hb1  = (const float*)d_in[14];
    const float* hW2  = (const float*)d_in[15];
    const float* hb2  = (const float*)d_in[16];
    const float* a1Wi = (const float*)d_in[17];
    const float* a1Wr = (const float*)d_in[18];
    const float* a1b  = (const float*)d_in[19];
    const float* a2Wi = (const float*)d_in[20];
    const float* a2Wr = (const float*)d_in[21];
    const float* a2b  = (const float*)d_in[22];
    const float* cW1  = (const float*)d_in[23];
    const float* cb1  = (const float*)d_in[24];
    const float* cW2  = (const float*)d_in[25];
    const float* cb2  = (const float*)d_in[26];
    const int*   eidx = (const int*)d_in[27];

    gnn_mb<<<NBLK, TPB, 0, stream>>>(x,
        lW1, lb1, lW2, lb2, mW1, mb1, mW2, mb2,
        jW1, jb1, jW2, jb2, hW1, hb1, hW2, hb2,
        a1Wi, a1Wr, a1b, a2Wi, a2Wr, a2b,
        cW1, cb1, cW2, cb2, eidx,
        (float*)d_out, (int*)d_ws, (float*)d_ws);
}